// Round 3
// baseline (163.979 us; speedup 1.0000x reference)
//
#include <hip/hip_runtime.h>

#define DIMC 1024
#define HEADS 16
#define HD 64
#define BATCH 2
#define SEQ 1024
#define NQKV 3072

typedef _Float16 f16;
typedef _Float16 half8 __attribute__((ext_vector_type(8)));
typedef _Float16 half4v __attribute__((ext_vector_type(4)));
typedef float floatx4 __attribute__((ext_vector_type(4)));

__device__ __forceinline__ void gld16(const void* g, void* l) {
  __builtin_amdgcn_global_load_lds((const __attribute__((address_space(1))) void*)g,
                                   (__attribute__((address_space(3))) void*)l, 16, 0, 0);
}

__device__ __forceinline__ unsigned sadU8(unsigned a, unsigned b, unsigned c) {
#if __has_builtin(__builtin_amdgcn_sad_u8)
  return __builtin_amdgcn_sad_u8(a, b, c);
#else
  unsigned d;
  asm("v_sad_u8 %0, %1, %2, %3" : "=v"(d) : "v"(a), "v"(b), "v"(c));
  return d;
#endif
}

// ---------------- f32 -> f16 casts (x, qkv_w, proj_w), 4 float4/thread ----------------
__global__ __launch_bounds__(256) void cvt_kernel(
    const float* __restrict__ x, const float* __restrict__ wq, const float* __restrict__ wp,
    f16* __restrict__ x16, f16* __restrict__ wq16, f16* __restrict__ wp16)
{
  int bid = blockIdx.x;
  const float* src; f16* dst; int base;
  if (bid < 512)        { src = x;  dst = x16;  base = bid; }
  else if (bid < 1280)  { src = wq; dst = wq16; base = bid - 512; }
  else                  { src = wp; dst = wp16; base = bid - 1280; }
  long long i0 = (long long)base*1024 + threadIdx.x;
#pragma unroll
  for (int k2 = 0; k2 < 4; ++k2) {
    long long i = i0 + k2*256;   // float4 index, coalesced
    float4 v = ((const float4*)src)[i];
    half4v h; h[0]=(f16)v.x; h[1]=(f16)v.y; h[2]=(f16)v.z; h[3]=(f16)v.w;
    *(half4v*)(dst + i*4) = h;
  }
}

// ---------------- TM x TN f16 MFMA GEMM (BK-deep K-tiles), C = A * Bw^T + bias ----
// MODE 0: QKV -> q8/k8 (u8 quant, [b,h,s,d]) and vT (f16, [b,h,d,s])
// MODE 1: proj -> f32 out [t, f]
template<int TM, int TN, int BK, int MW, int MODE>
__global__ __launch_bounds__(256, MW) void gemm_kernel(
    const f16* __restrict__ A, const f16* __restrict__ Bw, const float* __restrict__ bias,
    unsigned char* __restrict__ q8, unsigned char* __restrict__ k8, f16* __restrict__ vT,
    float* __restrict__ outp, int K)
{
  constexpr int MT = TM / 32;   // m-subtiles per wave
  constexpr int NT = TN / 32;   // n-subtiles per wave
  constexpr int G  = BK / 8;    // 16B groups per LDS row
  __shared__ f16 As[TM*BK];
  __shared__ f16 Bs[TN*BK];
  const int tid = threadIdx.x;
  const int wave = tid >> 6, lane = tid & 63;
  const int lq = lane >> 4, li = lane & 15;
  const int m0 = blockIdx.y * TM, n0 = blockIdx.x * TN;
  const int wm = (wave & 1) * (TM/2), wn = (wave >> 1) * (TN/2);
  floatx4 acc[MT][NT] = {};

  const int kIters = K / BK;
  for (int kt = 0; kt < kIters; ++kt) {
    __syncthreads();
#pragma unroll
    for (int r = 0; r < TM*BK/2048; ++r) {
      int slot = r*256 + tid;
      int row = slot / G, c = slot % G, g = c ^ (row & (G-1));
      gld16(A + (size_t)(m0+row)*K + kt*BK + g*8, As + slot*8);
    }
#pragma unroll
    for (int r = 0; r < TN*BK/2048; ++r) {
      int slot = r*256 + tid;
      int row = slot / G, c = slot % G, g = c ^ (row & (G-1));
      gld16(Bw + (size_t)(n0+row)*K + kt*BK + g*8, Bs + slot*8);
    }
    __syncthreads();
#pragma unroll
    for (int ks = 0; ks < BK/32; ++ks) {
      half8 af[MT], bf[NT];
      int kc = ks*4 + lq;
#pragma unroll
      for (int t = 0; t < MT; ++t) {
        int am = wm + t*16 + li;
        af[t] = *(const half8*)&As[am*BK + (kc ^ (am & (G-1)))*8];
      }
#pragma unroll
      for (int t = 0; t < NT; ++t) {
        int bn = wn + t*16 + li;
        bf[t] = *(const half8*)&Bs[bn*BK + (kc ^ (bn & (G-1)))*8];
      }
#pragma unroll
      for (int mt = 0; mt < MT; ++mt)
#pragma unroll
        for (int nt = 0; nt < NT; ++nt)
          acc[mt][nt] = __builtin_amdgcn_mfma_f32_16x16x32_f16(af[mt], bf[nt], acc[mt][nt], 0, 0, 0);
    }
  }

#pragma unroll
  for (int mt = 0; mt < MT; ++mt) {
#pragma unroll
    for (int nt = 0; nt < NT; ++nt) {
      int f = n0 + wn + nt*16 + li;                 // output feature (col, from B)
      float bb = bias[f];
      if (MODE == 0) {
        int which = f >> 10, cc = f & 1023, h = cc >> 6, d = cc & 63;
        int t0 = m0 + wm + mt*16 + lq*4;            // token (row, from A), 4 consecutive
        int b = t0 >> 10, s0 = t0 & 1023;
        if (which == 2) {
          half4v hv;
#pragma unroll
          for (int r = 0; r < 4; ++r) hv[r] = (f16)(acc[mt][nt][r] + bb);
          *(half4v*)&vT[((size_t)((b*HEADS + h)*HD + d))*SEQ + s0] = hv;
        } else {
          unsigned char* dst = (which == 0) ? q8 : k8;
#pragma unroll
          for (int r = 0; r < 4; ++r) {
            float v = acc[mt][nt][r] + bb;
            int u = (int)floorf(v * 16.0f + 128.5f);
            u = u < 0 ? 0 : (u > 255 ? 255 : u);
            dst[((size_t)((b*HEADS + h)*SEQ + s0 + r))*HD + d] = (unsigned char)u;
          }
        }
      } else {
#pragma unroll
        for (int r = 0; r < 4; ++r) {
          int t = m0 + wm + mt*16 + lq*4 + r;
          outp[(size_t)t*DIMC + f] = acc[mt][nt][r] + bb;
        }
      }
    }
  }
}

// ---------------- Laplacian attention + depthwise conv, y16 out ----------------
// R16: q8s/k8s LDS ELIMINATED. Evidence: R2 conflicts 4.03M (kk reads 8-way:
// 8 rows @ 256B stride = same bank-quad) and VGPR=128 proves qr[8][16] was
// being rematerialized from q8s (same 8-way pattern) every c4 iter. Both q and
// k are broadcast-read (8 lanes/chunk) and L2-resident (64KB/bh, 16 blocks
// share) -> read directly from global. Staging barrier moved AFTER phase-1 SAD
// so the vTs vmcnt(0) drain hides under ~1000cyc of SAD. LDS ~40.5KB.
__global__ __launch_bounds__(256, 2) void attn_kernel(
    const unsigned char* __restrict__ q8g, const unsigned char* __restrict__ k8g,
    const f16* __restrict__ vTg, const float* __restrict__ dwcw, const float* __restrict__ dwcb,
    f16* __restrict__ y16)
{
  __shared__ f16 vTs[64*128];            // 16KB  [d][j] swizzled
  __shared__ f16 sfrag[16*64*8];         // 16KB  scores in MFMA A-frag layout
  __shared__ float rspart[32*64];        //  8KB  [jslice][row]
  __shared__ float rowsum[64];           // total ~40.5KB

  const int tid = threadIdx.x;
  const int lin = blockIdx.x + 16 * blockIdx.y;
  const int bh = (lin & 7) * 4 + ((lin >> 3) & 3);   // XCD-grouped head index
  const int i0 = (lin >> 5) * 64;
  const int lane = tid & 63, wave = tid >> 6;
  const int lq = lane >> 4, li = lane & 15;
  // phase-1 mapping: 8 i-rows x 4 j-cols per thread
  const int iL8 = tid & 7;            // rows {iL8 + n*8}, n=0..7
  const int jt5 = tid >> 3;           // 0..31, j = jt5*4 + jj
  const int ksj = jt5 >> 3;           // k-slice 0..3
  const int qjp = (jt5 & 7) >> 1;     // k-group within slice
  const int e0  = (jt5 & 1) * 4;      // elem offset within half8 frag

  // q rows {iL8 + n*8} direct from global into regs (128 u32, no LDS source to
  // rematerialize from -> compiler must keep resident)
  unsigned qr[8][16];
  {
    const unsigned char* qbase = q8g + ((size_t)(bh*SEQ) + i0 + iL8)*HD;
#pragma unroll
    for (int n = 0; n < 8; ++n)
#pragma unroll
      for (int c4 = 0; c4 < 4; ++c4) {
        uint4 t = *(const uint4*)(qbase + (size_t)n*8*HD + c4*16);
        qr[n][c4*4+0] = t.x; qr[n][c4*4+1] = t.y; qr[n][c4*4+2] = t.z; qr[n][c4*4+3] = t.w;
      }
  }

  float rs[8] = {};
  floatx4 pacc[2][2] = {};
  const int mtb = (wave & 1) * 2, ntb = (wave >> 1) * 2;
  const unsigned char* kbase = k8g + ((size_t)(bh*SEQ) + jt5*4)*HD;

  for (int jb = 0; jb < 8; ++jb) {
    const int j0 = jb * 128;
    __syncthreads();                       // prev iter done with vTs/sfrag
#pragma unroll
    for (int r = 0; r < 4; ++r) {          // vT tile [64][128], xor swizzle
      int slot = r*256 + tid;
      int d = slot >> 4, c = slot & 15, sc = c ^ (d & 7);
      gld16(vTg + ((size_t)(bh*HD) + d)*SEQ + j0 + sc*8, vTs + slot*8);
    }
    // NO barrier here: phase 1 touches no LDS (k from global/L2). The vmcnt(0)
    // drain for vTs happens at the barrier AFTER SAD -> latency hidden.

    // ---- phase 1: SAD distances, 8 i x 4 j per thread, k from L2 ----
    unsigned sacc[8][4] = {};
#pragma unroll
    for (int c4 = 0; c4 < 4; ++c4) {
      uint4 kk[4];
#pragma unroll
      for (int jj = 0; jj < 4; ++jj)
        kk[jj] = *(const uint4*)(kbase + (size_t)(j0 + jj)*HD + c4*16);
#pragma unroll
      for (int n = 0; n < 8; ++n)
#pragma unroll
        for (int jj = 0; jj < 4; ++jj) {
          sacc[n][jj] = sadU8(qr[n][c4*4+0], kk[jj].x, sacc[n][jj]);
          sacc[n][jj] = sadU8(qr[n][c4*4+1], kk[jj].y, sacc[n][jj]);
          sacc[n][jj] = sadU8(qr[n][c4*4+2], kk[jj].z, sacc[n][jj]);
          sacc[n][jj] = sadU8(qr[n][c4*4+3], kk[jj].w, sacc[n][jj]);
        }
    }
    // kern = exp(-dist/16), dist = sad/16  ->  exp2(-sad * log2(e)/256)
#pragma unroll
    for (int n = 0; n < 8; ++n) {
      half4v sv;
#pragma unroll
      for (int jj = 0; jj < 4; ++jj) {
        float sf = exp2f(-0.0056355275f * (float)sacc[n][jj]);
        rs[n] += sf;
        sv[jj] = (f16)sf;
      }
      // A-frag layout: lane l holds row=l&15, k=(l>>4)*8+e of the ks-slice.
      int row = iL8 + n*8;
      int slot = ((row >> 4)*4 + ksj)*64 + qjp*16 + (row & 15);
      *(half4v*)&sfrag[slot*8 + e0] = sv;
    }
    __syncthreads();                       // sfrag ready + vTs landed (vmcnt drain)

    // ---- phase 2: PV via MFMA, wave tile 32i x 32d ----
#pragma unroll
    for (int ks = 0; ks < 4; ++ks) {
      half8 a0 = *(const half8*)&sfrag[(((mtb+0)*4 + ks)*64 + lane)*8];
      half8 a1 = *(const half8*)&sfrag[(((mtb+1)*4 + ks)*64 + lane)*8];
#pragma unroll
      for (int nt = 0; nt < 2; ++nt) {
        int d = (ntb + nt)*16 + li;
        int kc = ks*4 + lq;
        half8 bfr = *(const half8*)&vTs[d*128 + (kc ^ (d & 7))*8];
        pacc[0][nt] = __builtin_amdgcn_mfma_f32_16x16x32_f16(a0, bfr, pacc[0][nt], 0, 0, 0);
        pacc[1][nt] = __builtin_amdgcn_mfma_f32_16x16x32_f16(a1, bfr, pacc[1][nt], 0, 0, 0);
      }
    }
  }

  // rowsum reduction across the 32 j-slices (transposed: conflict-free read)
#pragma unroll
  for (int n = 0; n < 8; ++n) rspart[jt5*64 + iL8 + n*8] = rs[n];
  __syncthreads();
  if (tid < 64) {
    float s = 0.f;
#pragma unroll
    for (int t = 0; t < 32; ++t) s += rspart[t*64 + tid];
    rowsum[tid] = s + 1e-6f;
  }
  __syncthreads();

  // epilogue: normalize + depthwise conv + store y16 [b,s,h*64+d]
  // conv taps straight from vTg (L2-hit)
  const int b = bh >> 4, h = bh & 15;
#pragma unroll
  for (int nt = 0; nt < 2; ++nt) {
    int d = (ntb + nt)*16 + li;
    int c = h*64 + d;
    float w0 = dwcw[c*3+0], w1 = dwcw[c*3+1], w2 = dwcw[c*3+2], cb = dwcb[c];
    const f16* vrow = vTg + ((size_t)(bh*HD) + d)*SEQ;
#pragma unroll
    for (int mt = 0; mt < 2; ++mt) {
      int s0 = i0 + (mtb + mt)*16 + lq*4;          // first of 4 consecutive rows
      float vv[6];
#pragma unroll
      for (int e = 0; e < 6; ++e) {
        int s = s0 - 1 + e;
        vv[e] = (s >= 0 && s < SEQ) ? (float)vrow[s] : 0.f;
      }
#pragma unroll
      for (int r = 0; r < 4; ++r) {
        int ii = (mtb + mt)*16 + lq*4 + r;
        float val = pacc[mt][nt][r] / rowsum[ii];
        val += w0*vv[r] + w1*vv[r+1] + w2*vv[r+2] + cb;
        int s = i0 + ii;
        y16[((size_t)(b*SEQ + s))*DIMC + c] = (f16)val;
      }
    }
  }
}

extern "C" void kernel_launch(void* const* d_in, const int* in_sizes, int n_in,
                              void* d_out, int out_size, void* d_ws, size_t ws_size,
                              hipStream_t stream) {
  const float* x      = (const float*)d_in[0];
  const float* qkv_w  = (const float*)d_in[1];
  const float* qkv_b  = (const float*)d_in[2];
  const float* proj_w = (const float*)d_in[3];
  const float* proj_b = (const float*)d_in[4];
  const float* dwc_w  = (const float*)d_in[5];
  const float* dwc_b  = (const float*)d_in[6];
  float* out = (float*)d_out;

  char* ws = (char*)d_ws;
  f16* x16  = (f16*)(ws);                         //  4 MB
  f16* wq16 = (f16*)(ws + (4ll<<20));             //  6 MB
  f16* wp16 = (f16*)(ws + (10ll<<20));            //  2 MB
  unsigned char* q8 = (unsigned char*)(ws + (12ll<<20));  // 2 MB
  unsigned char* k8 = (unsigned char*)(ws + (14ll<<20));  // 2 MB
  f16* vT   = (f16*)(ws + (16ll<<20));            //  4 MB
  f16* y16  = (f16*)(ws + (20ll<<20));            //  4 MB (total 24 MB)

  cvt_kernel<<<1536, 256, 0, stream>>>(x, qkv_w, proj_w, x16, wq16, wp16);
  // gemm0: 128x128 tile, BK=128 (8 K-iters) — grid 24x16 = 384 blocks (proven)
  gemm_kernel<128,128,128,2,0><<<dim3(24, 16), 256, 0, stream>>>(x16, wq16, qkv_b, q8, k8, vT, nullptr, DIMC);
  attn_kernel<<<dim3(16, 32), 256, 0, stream>>>(q8, k8, vT, dwc_w, dwc_b, y16);
  // gemm1: 64x64 tile, BK=128 — grid 16x32 = 512 blocks
  gemm_kernel<64,64,128,4,1><<<dim3(16, 32), 256, 0, stream>>>(y16, wp16, proj_b, nullptr, nullptr, nullptr, out, DIMC);
}

// Round 4
// 151.585 us; speedup vs baseline: 1.0818x; 1.0818x over previous
//
#include <hip/hip_runtime.h>

#define DIMC 1024
#define HEADS 16
#define HD 64
#define BATCH 2
#define SEQ 1024
#define NQKV 3072

typedef _Float16 f16;
typedef _Float16 half8 __attribute__((ext_vector_type(8)));
typedef _Float16 half4v __attribute__((ext_vector_type(4)));
typedef float floatx4 __attribute__((ext_vector_type(4)));

__device__ __forceinline__ void gld16(const void* g, void* l) {
  __builtin_amdgcn_global_load_lds((const __attribute__((address_space(1))) void*)g,
                                   (__attribute__((address_space(3))) void*)l, 16, 0, 0);
}

__device__ __forceinline__ unsigned sadU8(unsigned a, unsigned b, unsigned c) {
#if __has_builtin(__builtin_amdgcn_sad_u8)
  return __builtin_amdgcn_sad_u8(a, b, c);
#else
  unsigned d;
  asm("v_sad_u8 %0, %1, %2, %3" : "=v"(d) : "v"(a), "v"(b), "v"(c));
  return d;
#endif
}

// ---------------- f32 -> f16 casts (x, qkv_w, proj_w), 4 float4/thread ----------------
__global__ __launch_bounds__(256) void cvt_kernel(
    const float* __restrict__ x, const float* __restrict__ wq, const float* __restrict__ wp,
    f16* __restrict__ x16, f16* __restrict__ wq16, f16* __restrict__ wp16)
{
  int bid = blockIdx.x;
  const float* src; f16* dst; int base;
  if (bid < 512)        { src = x;  dst = x16;  base = bid; }
  else if (bid < 1280)  { src = wq; dst = wq16; base = bid - 512; }
  else                  { src = wp; dst = wp16; base = bid - 1280; }
  long long i0 = (long long)base*1024 + threadIdx.x;
#pragma unroll
  for (int k2 = 0; k2 < 4; ++k2) {
    long long i = i0 + k2*256;   // float4 index, coalesced
    float4 v = ((const float4*)src)[i];
    half4v h; h[0]=(f16)v.x; h[1]=(f16)v.y; h[2]=(f16)v.z; h[3]=(f16)v.w;
    *(half4v*)(dst + i*4) = h;
  }
}

// ---------------- TM x TN f16 MFMA GEMM (BK-deep K-tiles), C = A * Bw^T + bias ----
// MODE 0: QKV -> q8/k8 (u8 quant, [b,h,s,d]) and vT (f16, [b,h,d,s])
// MODE 1: proj -> f32 out [t, f]
// R17: residency fix. gemm0 128x64 tile (grid 768 = 3 blocks/CU, MW=3, BK=128
// unchanged -> same barrier count/block, but other blocks' waves now hide each
// block's vmcnt(0)+barrier drain — the m114 overlap mechanism R14 failed to
// exploit because its grid stayed at 384). gemm1 64x64 BK=64, MW=4 (LDS 16KB,
// 4 blocks/CU).
template<int TM, int TN, int BK, int MW, int MODE>
__global__ __launch_bounds__(256, MW) void gemm_kernel(
    const f16* __restrict__ A, const f16* __restrict__ Bw, const float* __restrict__ bias,
    unsigned char* __restrict__ q8, unsigned char* __restrict__ k8, f16* __restrict__ vT,
    float* __restrict__ outp, int K)
{
  constexpr int MT = TM / 32;   // m-subtiles per wave
  constexpr int NT = TN / 32;   // n-subtiles per wave
  constexpr int G  = BK / 8;    // 16B groups per LDS row
  __shared__ f16 As[TM*BK];
  __shared__ f16 Bs[TN*BK];
  const int tid = threadIdx.x;
  const int wave = tid >> 6, lane = tid & 63;
  const int lq = lane >> 4, li = lane & 15;
  const int m0 = blockIdx.y * TM, n0 = blockIdx.x * TN;
  const int wm = (wave & 1) * (TM/2), wn = (wave >> 1) * (TN/2);
  floatx4 acc[MT][NT] = {};

  const int kIters = K / BK;
  for (int kt = 0; kt < kIters; ++kt) {
    __syncthreads();
#pragma unroll
    for (int r = 0; r < TM*BK/2048; ++r) {
      int slot = r*256 + tid;
      int row = slot / G, c = slot % G, g = c ^ (row & (G-1));
      gld16(A + (size_t)(m0+row)*K + kt*BK + g*8, As + slot*8);
    }
#pragma unroll
    for (int r = 0; r < TN*BK/2048; ++r) {
      int slot = r*256 + tid;
      int row = slot / G, c = slot % G, g = c ^ (row & (G-1));
      gld16(Bw + (size_t)(n0+row)*K + kt*BK + g*8, Bs + slot*8);
    }
    __syncthreads();
#pragma unroll
    for (int ks = 0; ks < BK/32; ++ks) {
      half8 af[MT], bf[NT];
      int kc = ks*4 + lq;
#pragma unroll
      for (int t = 0; t < MT; ++t) {
        int am = wm + t*16 + li;
        af[t] = *(const half8*)&As[am*BK + (kc ^ (am & (G-1)))*8];
      }
#pragma unroll
      for (int t = 0; t < NT; ++t) {
        int bn = wn + t*16 + li;
        bf[t] = *(const half8*)&Bs[bn*BK + (kc ^ (bn & (G-1)))*8];
      }
#pragma unroll
      for (int mt = 0; mt < MT; ++mt)
#pragma unroll
        for (int nt = 0; nt < NT; ++nt)
          acc[mt][nt] = __builtin_amdgcn_mfma_f32_16x16x32_f16(af[mt], bf[nt], acc[mt][nt], 0, 0, 0);
    }
  }

#pragma unroll
  for (int mt = 0; mt < MT; ++mt) {
#pragma unroll
    for (int nt = 0; nt < NT; ++nt) {
      int f = n0 + wn + nt*16 + li;                 // output feature (col, from B)
      float bb = bias[f];
      if (MODE == 0) {
        int which = f >> 10, cc = f & 1023, h = cc >> 6, d = cc & 63;
        int t0 = m0 + wm + mt*16 + lq*4;            // token (row, from A), 4 consecutive
        int b = t0 >> 10, s0 = t0 & 1023;
        if (which == 2) {
          half4v hv;
#pragma unroll
          for (int r = 0; r < 4; ++r) hv[r] = (f16)(acc[mt][nt][r] + bb);
          *(half4v*)&vT[((size_t)((b*HEADS + h)*HD + d))*SEQ + s0] = hv;
        } else {
          unsigned char* dst = (which == 0) ? q8 : k8;
#pragma unroll
          for (int r = 0; r < 4; ++r) {
            float v = acc[mt][nt][r] + bb;
            int u = (int)floorf(v * 16.0f + 128.5f);
            u = u < 0 ? 0 : (u > 255 ? 255 : u);
            dst[((size_t)((b*HEADS + h)*SEQ + s0 + r))*HD + d] = (unsigned char)u;
          }
        }
      } else {
#pragma unroll
        for (int r = 0; r < 4; ++r) {
          int t = m0 + wm + mt*16 + lq*4 + r;
          outp[(size_t)t*DIMC + f] = acc[mt][nt][r] + bb;
        }
      }
    }
  }
}

// ---------------- Laplacian attention + depthwise conv, y16 out ----------------
// R17: attn reverted to the proven R14/R1 version (45.3us, VGPR 84, LDS 49664).
// R16's global-k/q-in-regs arc FAILED: compiler pins VGPR at 128 -> qr spilled
// to scratch (WRITE_SIZE 4.6->12.3MB = spill traffic) and uncoalesced L2 k-reads
// added unhidden latency at 8 waves/CU. Conflicted-LDS kk reads (~3.1M) remain,
// but both retile (R15) and de-LDS (R16) attempts proved neutral-or-worse.
__global__ __launch_bounds__(256, 3) void attn_kernel(
    const unsigned char* __restrict__ q8g, const unsigned char* __restrict__ k8g,
    const f16* __restrict__ vTg, const float* __restrict__ dwcw, const float* __restrict__ dwcb,
    f16* __restrict__ y16)
{
  __shared__ unsigned char q8s[64*64];   //  4KB
  __shared__ unsigned char k8s[128*64];  //  8KB
  __shared__ f16 vTs[64*128];            // 16KB  [d][j] swizzled
  __shared__ f16 sfrag[16*64*8];         // 16KB  scores in MFMA A-frag layout
  __shared__ float rspart[64*16];        //  4KB
  __shared__ float rowsum[64];           // total 49408B

  const int tid = threadIdx.x;
  const int lin = blockIdx.x + 16 * blockIdx.y;
  const int bh = (lin & 7) * 4 + ((lin >> 3) & 3);   // XCD-grouped head index
  const int i0 = (lin >> 5) * 64;
  const int lane = tid & 63, wave = tid >> 6;
  const int lq = lane >> 4, li = lane & 15;
  const int iL = tid & 15, jt = tid >> 4;       // phase-1 mapping
  const int ksj = jt >> 2, qj = jt & 3;

  { // stage q tile: 64 rows x 64B
    gld16(q8g + ((size_t)(bh*SEQ) + i0)*HD + tid*16, q8s + tid*16);
  }
  __syncthreads();

  // q rows {iL, iL+16, iL+32, iL+48} into regs (64 u32)
  unsigned qr[4][16];
#pragma unroll
  for (int n = 0; n < 4; ++n)
#pragma unroll
    for (int c4 = 0; c4 < 4; ++c4) {
      uint4 t = *(const uint4*)&q8s[(iL + n*16)*64 + c4*16];
      qr[n][c4*4+0] = t.x; qr[n][c4*4+1] = t.y; qr[n][c4*4+2] = t.z; qr[n][c4*4+3] = t.w;
    }

  float rs[4] = {0.f, 0.f, 0.f, 0.f};
  floatx4 pacc[2][2] = {};
  const int mtb = (wave & 1) * 2, ntb = (wave >> 1) * 2;

  for (int jb = 0; jb < 8; ++jb) {
    const int j0 = jb * 128;
    __syncthreads();                       // prev iter done with k8s/vTs/sfrag
#pragma unroll
    for (int r = 0; r < 2; ++r) {          // k tile: 128 rows x 64B
      int slot = r*256 + tid;
      gld16(k8g + ((size_t)(bh*SEQ) + j0)*HD + slot*16, k8s + slot*16);
    }
#pragma unroll
    for (int r = 0; r < 4; ++r) {          // vT tile [64][128], xor swizzle
      int slot = r*256 + tid;
      int d = slot >> 4, c = slot & 15, sc = c ^ (d & 7);
      gld16(vTg + ((size_t)(bh*HD) + d)*SEQ + j0 + sc*8, vTs + slot*8);
    }
    __syncthreads();                       // staging complete

    // ---- phase 1: SAD distances, 4 i x 8 j per thread ----
    unsigned sacc[4][8] = {};
#pragma unroll
    for (int c4 = 0; c4 < 4; ++c4) {
      uint4 kk[8];
#pragma unroll
      for (int jj = 0; jj < 8; ++jj)
        kk[jj] = *(const uint4*)&k8s[(jt*8 + jj)*64 + c4*16];   // 16-lane broadcast
#pragma unroll
      for (int n = 0; n < 4; ++n)
#pragma unroll
        for (int jj = 0; jj < 8; ++jj) {
          sacc[n][jj] = sadU8(qr[n][c4*4+0], kk[jj].x, sacc[n][jj]);
          sacc[n][jj] = sadU8(qr[n][c4*4+1], kk[jj].y, sacc[n][jj]);
          sacc[n][jj] = sadU8(qr[n][c4*4+2], kk[jj].z, sacc[n][jj]);
          sacc[n][jj] = sadU8(qr[n][c4*4+3], kk[jj].w, sacc[n][jj]);
        }
    }
    // kern = exp(-dist/16), dist = sad/16  ->  exp2(-sad * log2(e)/256)
#pragma unroll
    for (int n = 0; n < 4; ++n) {
      half8 sv;
#pragma unroll
      for (int jj = 0; jj < 8; ++jj) {
        float sf = exp2f(-0.0056355275f * (float)sacc[n][jj]);
        rs[n] += sf;
        sv[jj] = (f16)sf;
      }
      // A-frag layout: slot = (mt*4 + ks)*64 + lane, lane = qj*16 + iL (lane-contiguous)
      *(half8*)&sfrag[((n*4 + ksj)*64 + qj*16 + iL)*8] = sv;
    }
    __syncthreads();                       // scores ready

    // ---- phase 2: PV via MFMA, wave tile 32i x 32d ----
#pragma unroll
    for (int ks = 0; ks < 4; ++ks) {
      half8 a0 = *(const half8*)&sfrag[(((mtb+0)*4 + ks)*64 + lane)*8];
      half8 a1 = *(const half8*)&sfrag[(((mtb+1)*4 + ks)*64 + lane)*8];
#pragma unroll
      for (int nt = 0; nt < 2; ++nt) {
        int d = (ntb + nt)*16 + li;
        int kc = ks*4 + lq;
        half8 bfr = *(const half8*)&vTs[d*128 + (kc ^ (d & 7))*8];
        pacc[0][nt] = __builtin_amdgcn_mfma_f32_16x16x32_f16(a0, bfr, pacc[0][nt], 0, 0, 0);
        pacc[1][nt] = __builtin_amdgcn_mfma_f32_16x16x32_f16(a1, bfr, pacc[1][nt], 0, 0, 0);
      }
    }
  }

  // rowsum reduction across the 16 j-slices
#pragma unroll
  for (int n = 0; n < 4; ++n) rspart[(iL + n*16)*16 + jt] = rs[n];
  __syncthreads();
  if (tid < 64) {
    float s = 0.f;
#pragma unroll
    for (int t = 0; t < 16; ++t) s += rspart[tid*16 + t];
    rowsum[tid] = s + 1e-6f;
  }
  __syncthreads();

  // epilogue: normalize + depthwise conv + store y16 [b,s,h*64+d]
  // conv taps straight from vTg (L2-hit)
  const int b = bh >> 4, h = bh & 15;
#pragma unroll
  for (int nt = 0; nt < 2; ++nt) {
    int d = (ntb + nt)*16 + li;
    int c = h*64 + d;
    float w0 = dwcw[c*3+0], w1 = dwcw[c*3+1], w2 = dwcw[c*3+2], cb = dwcb[c];
    const f16* vrow = vTg + ((size_t)(bh*HD) + d)*SEQ;
#pragma unroll
    for (int mt = 0; mt < 2; ++mt) {
      int s0 = i0 + (mtb + mt)*16 + lq*4;          // first of 4 consecutive rows
      float vv[6];
#pragma unroll
      for (int e = 0; e < 6; ++e) {
        int s = s0 - 1 + e;
        vv[e] = (s >= 0 && s < SEQ) ? (float)vrow[s] : 0.f;
      }
#pragma unroll
      for (int r = 0; r < 4; ++r) {
        int ii = (mtb + mt)*16 + lq*4 + r;
        float val = pacc[mt][nt][r] / rowsum[ii];
        val += w0*vv[r] + w1*vv[r+1] + w2*vv[r+2] + cb;
        int s = i0 + ii;
        y16[((size_t)(b*SEQ + s))*DIMC + c] = (f16)val;
      }
    }
  }
}

extern "C" void kernel_launch(void* const* d_in, const int* in_sizes, int n_in,
                              void* d_out, int out_size, void* d_ws, size_t ws_size,
                              hipStream_t stream) {
  const float* x      = (const float*)d_in[0];
  const float* qkv_w  = (const float*)d_in[1];
  const float* qkv_b  = (const float*)d_in[2];
  const float* proj_w = (const float*)d_in[3];
  const float* proj_b = (const float*)d_in[4];
  const float* dwc_w  = (const float*)d_in[5];
  const float* dwc_b  = (const float*)d_in[6];
  float* out = (float*)d_out;

  char* ws = (char*)d_ws;
  f16* x16  = (f16*)(ws);                         //  4 MB
  f16* wq16 = (f16*)(ws + (4ll<<20));             //  6 MB
  f16* wp16 = (f16*)(ws + (10ll<<20));            //  2 MB
  unsigned char* q8 = (unsigned char*)(ws + (12ll<<20));  // 2 MB
  unsigned char* k8 = (unsigned char*)(ws + (14ll<<20));  // 2 MB
  f16* vT   = (f16*)(ws + (16ll<<20));            //  4 MB
  f16* y16  = (f16*)(ws + (20ll<<20));            //  4 MB (total 24 MB)

  cvt_kernel<<<1536, 256, 0, stream>>>(x, qkv_w, proj_w, x16, wq16, wp16);
  // gemm0: 128x64 tile, BK=128 — grid 48x16 = 768 blocks = 3/CU
  gemm_kernel<128,64,128,3,0><<<dim3(48, 16), 256, 0, stream>>>(x16, wq16, qkv_b, q8, k8, vT, nullptr, DIMC);
  attn_kernel<<<dim3(16, 32), 256, 0, stream>>>(q8, k8, vT, dwc_w, dwc_b, y16);
  // gemm1: 64x64 tile, BK=64 — grid 16x32 = 512 blocks, MW=4 -> 4 blocks/CU
  gemm_kernel<64,64,64,4,1><<<dim3(16, 32), 256, 0, stream>>>(y16, wp16, proj_b, nullptr, nullptr, nullptr, out, DIMC);
}

// Round 6
// 150.077 us; speedup vs baseline: 1.0926x; 1.0100x over previous
//
#include <hip/hip_runtime.h>

#define DIMC 1024
#define HEADS 16
#define HD 64
#define BATCH 2
#define SEQ 1024
#define NQKV 3072

typedef _Float16 f16;
typedef _Float16 half8 __attribute__((ext_vector_type(8)));
typedef _Float16 half4v __attribute__((ext_vector_type(4)));
typedef float floatx4 __attribute__((ext_vector_type(4)));

__device__ __forceinline__ void gld16(const void* g, void* l) {
  __builtin_amdgcn_global_load_lds((const __attribute__((address_space(1))) void*)g,
                                   (__attribute__((address_space(3))) void*)l, 16, 0, 0);
}

__device__ __forceinline__ unsigned sadU8(unsigned a, unsigned b, unsigned c) {
#if __has_builtin(__builtin_amdgcn_sad_u8)
  return __builtin_amdgcn_sad_u8(a, b, c);
#else
  unsigned d;
  asm("v_sad_u8 %0, %1, %2, %3" : "=v"(d) : "v"(a), "v"(b), "v"(c));
  return d;
#endif
}

// ---------------- f32 -> f16 casts (x, qkv_w, proj_w), 4 float4/thread ----------------
__global__ __launch_bounds__(256) void cvt_kernel(
    const float* __restrict__ x, const float* __restrict__ wq, const float* __restrict__ wp,
    f16* __restrict__ x16, f16* __restrict__ wq16, f16* __restrict__ wp16)
{
  int bid = blockIdx.x;
  const float* src; f16* dst; int base;
  if (bid < 512)        { src = x;  dst = x16;  base = bid; }
  else if (bid < 1280)  { src = wq; dst = wq16; base = bid - 512; }
  else                  { src = wp; dst = wp16; base = bid - 1280; }
  long long i0 = (long long)base*1024 + threadIdx.x;
#pragma unroll
  for (int k2 = 0; k2 < 4; ++k2) {
    long long i = i0 + k2*256;   // float4 index, coalesced
    float4 v = ((const float4*)src)[i];
    half4v h; h[0]=(f16)v.x; h[1]=(f16)v.y; h[2]=(f16)v.z; h[3]=(f16)v.w;
    *(half4v*)(dst + i*4) = h;
  }
}

// ---------------- TM x TN f16 MFMA GEMM (BK-deep K-tiles), C = A * Bw^T + bias ----
// MODE 0: QKV -> q8/k8 (u8 quant, [b,h,s,d]) and vT (f16, [b,h,d,s])
// MODE 1: proj -> f32 out [t, f]
// R18: gemm configs reverted to the R0/R2-proven set (gemm0 128x128 BK128 MW2,
// gemm1 64x64 BK128 MW4). Three rounds of gemm tiling/residency changes were
// all neutral (+-2us) -> gemms are not the binding constraint at these shapes.
template<int TM, int TN, int BK, int MW, int MODE>
__global__ __launch_bounds__(256, MW) void gemm_kernel(
    const f16* __restrict__ A, const f16* __restrict__ Bw, const float* __restrict__ bias,
    unsigned char* __restrict__ q8, unsigned char* __restrict__ k8, f16* __restrict__ vT,
    float* __restrict__ outp, int K)
{
  constexpr int MT = TM / 32;   // m-subtiles per wave
  constexpr int NT = TN / 32;   // n-subtiles per wave
  constexpr int G  = BK / 8;    // 16B groups per LDS row
  __shared__ f16 As[TM*BK];
  __shared__ f16 Bs[TN*BK];
  const int tid = threadIdx.x;
  const int wave = tid >> 6, lane = tid & 63;
  const int lq = lane >> 4, li = lane & 15;
  const int m0 = blockIdx.y * TM, n0 = blockIdx.x * TN;
  const int wm = (wave & 1) * (TM/2), wn = (wave >> 1) * (TN/2);
  floatx4 acc[MT][NT] = {};

  const int kIters = K / BK;
  for (int kt = 0; kt < kIters; ++kt) {
    __syncthreads();
#pragma unroll
    for (int r = 0; r < TM*BK/2048; ++r) {
      int slot = r*256 + tid;
      int row = slot / G, c = slot % G, g = c ^ (row & (G-1));
      gld16(A + (size_t)(m0+row)*K + kt*BK + g*8, As + slot*8);
    }
#pragma unroll
    for (int r = 0; r < TN*BK/2048; ++r) {
      int slot = r*256 + tid;
      int row = slot / G, c = slot % G, g = c ^ (row & (G-1));
      gld16(Bw + (size_t)(n0+row)*K + kt*BK + g*8, Bs + slot*8);
    }
    __syncthreads();
#pragma unroll
    for (int ks = 0; ks < BK/32; ++ks) {
      half8 af[MT], bf[NT];
      int kc = ks*4 + lq;
#pragma unroll
      for (int t = 0; t < MT; ++t) {
        int am = wm + t*16 + li;
        af[t] = *(const half8*)&As[am*BK + (kc ^ (am & (G-1)))*8];
      }
#pragma unroll
      for (int t = 0; t < NT; ++t) {
        int bn = wn + t*16 + li;
        bf[t] = *(const half8*)&Bs[bn*BK + (kc ^ (bn & (G-1)))*8];
      }
#pragma unroll
      for (int mt = 0; mt < MT; ++mt)
#pragma unroll
        for (int nt = 0; nt < NT; ++nt)
          acc[mt][nt] = __builtin_amdgcn_mfma_f32_16x16x32_f16(af[mt], bf[nt], acc[mt][nt], 0, 0, 0);
    }
  }

#pragma unroll
  for (int mt = 0; mt < MT; ++mt) {
#pragma unroll
    for (int nt = 0; nt < NT; ++nt) {
      int f = n0 + wn + nt*16 + li;                 // output feature (col, from B)
      float bb = bias[f];
      if (MODE == 0) {
        int which = f >> 10, cc = f & 1023, h = cc >> 6, d = cc & 63;
        int t0 = m0 + wm + mt*16 + lq*4;            // token (row, from A), 4 consecutive
        int b = t0 >> 10, s0 = t0 & 1023;
        if (which == 2) {
          half4v hv;
#pragma unroll
          for (int r = 0; r < 4; ++r) hv[r] = (f16)(acc[mt][nt][r] + bb);
          *(half4v*)&vT[((size_t)((b*HEADS + h)*HD + d))*SEQ + s0] = hv;
        } else {
          unsigned char* dst = (which == 0) ? q8 : k8;
#pragma unroll
          for (int r = 0; r < 4; ++r) {
            float v = acc[mt][nt][r] + bb;
            int u = (int)floorf(v * 16.0f + 128.5f);
            u = u < 0 ? 0 : (u > 255 ? 255 : u);
            dst[((size_t)((b*HEADS + h)*SEQ + s0 + r))*HD + d] = (unsigned char)u;
          }
        }
      } else {
#pragma unroll
        for (int r = 0; r < 4; ++r) {
          int t = m0 + wm + mt*16 + lq*4 + r;
          outp[(size_t)t*DIMC + f] = acc[mt][nt][r] + bb;
        }
      }
    }
  }
}

// ---------------- Laplacian attention + depthwise conv, y16 out ----------------
// R18 (resubmitted unchanged after R5 infra failure — "container failed twice"
// is an acquisition error; kernel audit found no fault: q-stage branch is
// wave-uniform, sfrag slots 0-511 in-range, LDS 36992B, no sync in launch).
// q-tile split 64 -> 32 rows/block. Grid 512 -> 1024 blocks (= 4/CU).
// Occupancy was GRID-limited (512 blocks = exactly 2/CU). q-rows are
// embarrassingly parallel; only the j loop is a reduction. Per-block: LDS
// 49.4 -> ~36.4KB, qr halves to 32 VGPRs, SAD/MFMA work halves, staging
// volume per block unchanged (L2-absorbed; 32 blocks/bh share one XCD's L2).
__global__ __launch_bounds__(256, 4) void attn_kernel(
    const unsigned char* __restrict__ q8g, const unsigned char* __restrict__ k8g,
    const f16* __restrict__ vTg, const float* __restrict__ dwcw, const float* __restrict__ dwcb,
    f16* __restrict__ y16)
{
  __shared__ unsigned char q8s[32*64];   //  2KB
  __shared__ unsigned char k8s[128*64];  //  8KB
  __shared__ f16 vTs[64*128];            // 16KB  [d][j] swizzled
  __shared__ f16 sfrag[8*64*8];          //  8KB  scores in MFMA A-frag layout
  __shared__ float rspart[32*16];        //  2KB
  __shared__ float rowsum[32];           // total ~36.4KB -> 4 blocks/CU

  const int tid = threadIdx.x;
  const int lin = blockIdx.x + 16 * blockIdx.y;      // 0..1023
  const int bh = (lin & 7) * 4 + ((lin >> 3) & 3);   // XCD-grouped head index
  const int i0 = (lin >> 5) * 32;                    // 32 i-blocks of 32 rows
  const int lane = tid & 63, wave = tid >> 6;
  const int lq = lane >> 4, li = lane & 15;
  const int iL = tid & 15, jt = tid >> 4;       // phase-1 mapping
  const int ksj = jt >> 2, qj = jt & 3;

  { // stage q tile: 32 rows x 64B = 2KB (waves 0-1 only; wave-uniform branch)
    if (tid < 128)
      gld16(q8g + ((size_t)(bh*SEQ) + i0)*HD + tid*16, q8s + tid*16);
  }
  __syncthreads();

  // q rows {iL, iL+16} into regs (32 u32)
  unsigned qr[2][16];
#pragma unroll
  for (int n = 0; n < 2; ++n)
#pragma unroll
    for (int c4 = 0; c4 < 4; ++c4) {
      uint4 t = *(const uint4*)&q8s[(iL + n*16)*64 + c4*16];
      qr[n][c4*4+0] = t.x; qr[n][c4*4+1] = t.y; qr[n][c4*4+2] = t.z; qr[n][c4*4+3] = t.w;
    }

  float rs[2] = {0.f, 0.f};
  floatx4 pacc[2] = {};                  // [mt] ; this wave owns d-strip wave*16..+15

  for (int jb = 0; jb < 8; ++jb) {
    const int j0 = jb * 128;
    __syncthreads();                       // prev iter done with k8s/vTs/sfrag
#pragma unroll
    for (int r = 0; r < 2; ++r) {          // k tile: 128 rows x 64B
      int slot = r*256 + tid;
      gld16(k8g + ((size_t)(bh*SEQ) + j0)*HD + slot*16, k8s + slot*16);
    }
#pragma unroll
    for (int r = 0; r < 4; ++r) {          // vT tile [64][128], xor swizzle
      int slot = r*256 + tid;
      int d = slot >> 4, c = slot & 15, sc = c ^ (d & 7);
      gld16(vTg + ((size_t)(bh*HD) + d)*SEQ + j0 + sc*8, vTs + slot*8);
    }
    __syncthreads();                       // staging complete

    // ---- phase 1: SAD distances, 2 i x 8 j per thread ----
    unsigned sacc[2][8] = {};
#pragma unroll
    for (int c4 = 0; c4 < 4; ++c4) {
      uint4 kk[8];
#pragma unroll
      for (int jj = 0; jj < 8; ++jj)
        kk[jj] = *(const uint4*)&k8s[(jt*8 + jj)*64 + c4*16];   // 16-lane broadcast
#pragma unroll
      for (int n = 0; n < 2; ++n)
#pragma unroll
        for (int jj = 0; jj < 8; ++jj) {
          sacc[n][jj] = sadU8(qr[n][c4*4+0], kk[jj].x, sacc[n][jj]);
          sacc[n][jj] = sadU8(qr[n][c4*4+1], kk[jj].y, sacc[n][jj]);
          sacc[n][jj] = sadU8(qr[n][c4*4+2], kk[jj].z, sacc[n][jj]);
          sacc[n][jj] = sadU8(qr[n][c4*4+3], kk[jj].w, sacc[n][jj]);
        }
    }
    // kern = exp(-dist/16), dist = sad/16  ->  exp2(-sad * log2(e)/256)
#pragma unroll
    for (int n = 0; n < 2; ++n) {
      half8 sv;
#pragma unroll
      for (int jj = 0; jj < 8; ++jj) {
        float sf = exp2f(-0.0056355275f * (float)sacc[n][jj]);
        rs[n] += sf;
        sv[jj] = (f16)sf;
      }
      // A-frag layout: slot = (mt*4 + ks)*64 + lane, lane = qj*16 + iL
      *(half8*)&sfrag[((n*4 + ksj)*64 + qj*16 + iL)*8] = sv;
    }
    __syncthreads();                       // scores ready

    // ---- phase 2: PV via MFMA, wave tile 32i x 16d ----
#pragma unroll
    for (int ks = 0; ks < 4; ++ks) {
      half8 a0 = *(const half8*)&sfrag[((0*4 + ks)*64 + lane)*8];
      half8 a1 = *(const half8*)&sfrag[((1*4 + ks)*64 + lane)*8];
      int d = wave*16 + li;
      int kc = ks*4 + lq;
      half8 bfr = *(const half8*)&vTs[d*128 + (kc ^ (d & 7))*8];
      pacc[0] = __builtin_amdgcn_mfma_f32_16x16x32_f16(a0, bfr, pacc[0], 0, 0, 0);
      pacc[1] = __builtin_amdgcn_mfma_f32_16x16x32_f16(a1, bfr, pacc[1], 0, 0, 0);
    }
  }

  // rowsum reduction across the 16 j-slices
#pragma unroll
  for (int n = 0; n < 2; ++n) rspart[(iL + n*16)*16 + jt] = rs[n];
  __syncthreads();
  if (tid < 32) {
    float s = 0.f;
#pragma unroll
    for (int t = 0; t < 16; ++t) s += rspart[tid*16 + t];
    rowsum[tid] = s + 1e-6f;
  }
  __syncthreads();

  // epilogue: normalize + depthwise conv + store y16 [b,s,h*64+d]
  // conv taps straight from vTg (L2-hit)
  const int b = bh >> 4, h = bh & 15;
  {
    int d = wave*16 + li;
    int c = h*64 + d;
    float w0 = dwcw[c*3+0], w1 = dwcw[c*3+1], w2 = dwcw[c*3+2], cb = dwcb[c];
    const f16* vrow = vTg + ((size_t)(bh*HD) + d)*SEQ;
#pragma unroll
    for (int mt = 0; mt < 2; ++mt) {
      int s0 = i0 + mt*16 + lq*4;                  // first of 4 consecutive rows
      float vv[6];
#pragma unroll
      for (int e = 0; e < 6; ++e) {
        int s = s0 - 1 + e;
        vv[e] = (s >= 0 && s < SEQ) ? (float)vrow[s] : 0.f;
      }
#pragma unroll
      for (int r = 0; r < 4; ++r) {
        int ii = mt*16 + lq*4 + r;
        float val = pacc[mt][r] / rowsum[ii];
        val += w0*vv[r] + w1*vv[r+1] + w2*vv[r+2] + cb;
        int s = i0 + ii;
        y16[((size_t)(b*SEQ + s))*DIMC + c] = (f16)val;
      }
    }
  }
}

extern "C" void kernel_launch(void* const* d_in, const int* in_sizes, int n_in,
                              void* d_out, int out_size, void* d_ws, size_t ws_size,
                              hipStream_t stream) {
  const float* x      = (const float*)d_in[0];
  const float* qkv_w  = (const float*)d_in[1];
  const float* qkv_b  = (const float*)d_in[2];
  const float* proj_w = (const float*)d_in[3];
  const float* proj_b = (const float*)d_in[4];
  const float* dwc_w  = (const float*)d_in[5];
  const float* dwc_b  = (const float*)d_in[6];
  float* out = (float*)d_out;

  char* ws = (char*)d_ws;
  f16* x16  = (f16*)(ws);                         //  4 MB
  f16* wq16 = (f16*)(ws + (4ll<<20));             //  6 MB
  f16* wp16 = (f16*)(ws + (10ll<<20));            //  2 MB
  unsigned char* q8 = (unsigned char*)(ws + (12ll<<20));  // 2 MB
  unsigned char* k8 = (unsigned char*)(ws + (14ll<<20));  // 2 MB
  f16* vT   = (f16*)(ws + (16ll<<20));            //  4 MB
  f16* y16  = (f16*)(ws + (20ll<<20));            //  4 MB (total 24 MB)

  cvt_kernel<<<1536, 256, 0, stream>>>(x, qkv_w, proj_w, x16, wq16, wp16);
  // gemm0: 128x128 tile, BK=128 (8 K-iters) — grid 24x16 = 384 blocks (proven)
  gemm_kernel<128,128,128,2,0><<<dim3(24, 16), 256, 0, stream>>>(x16, wq16, qkv_b, q8, k8, vT, nullptr, DIMC);
  // attn: 1024 blocks (32 bh x 32 i-blocks of 32 rows) = 4 blocks/CU
  attn_kernel<<<dim3(16, 64), 256, 0, stream>>>(q8, k8, vT, dwc_w, dwc_b, y16);
  // gemm1: 64x64 tile, BK=128 — grid 16x32 = 512 blocks (proven)
  gemm_kernel<64,64,128,4,1><<<dim3(16, 32), 256, 0, stream>>>(y16, wp16, proj_b, nullptr, nullptr, nullptr, out, DIMC);
}

// Round 7
// 146.470 us; speedup vs baseline: 1.1195x; 1.0246x over previous
//
#include <hip/hip_runtime.h>

#define DIMC 1024
#define HEADS 16
#define HD 64
#define BATCH 2
#define SEQ 1024
#define NQKV 3072

typedef _Float16 f16;
typedef _Float16 half8 __attribute__((ext_vector_type(8)));
typedef _Float16 half4v __attribute__((ext_vector_type(4)));
typedef float floatx4 __attribute__((ext_vector_type(4)));

__device__ __forceinline__ void gld16(const void* g, void* l) {
  __builtin_amdgcn_global_load_lds((const __attribute__((address_space(1))) void*)g,
                                   (__attribute__((address_space(3))) void*)l, 16, 0, 0);
}

__device__ __forceinline__ unsigned sadU8(unsigned a, unsigned b, unsigned c) {
#if __has_builtin(__builtin_amdgcn_sad_u8)
  return __builtin_amdgcn_sad_u8(a, b, c);
#else
  unsigned d;
  asm("v_sad_u8 %0, %1, %2, %3" : "=v"(d) : "v"(a), "v"(b), "v"(c));
  return d;
#endif
}

// ---------------- f32 -> f16 casts (x, qkv_w, proj_w), 4 float4/thread ----------------
__global__ __launch_bounds__(256) void cvt_kernel(
    const float* __restrict__ x, const float* __restrict__ wq, const float* __restrict__ wp,
    f16* __restrict__ x16, f16* __restrict__ wq16, f16* __restrict__ wp16)
{
  int bid = blockIdx.x;
  const float* src; f16* dst; int base;
  if (bid < 512)        { src = x;  dst = x16;  base = bid; }
  else if (bid < 1280)  { src = wq; dst = wq16; base = bid - 512; }
  else                  { src = wp; dst = wp16; base = bid - 1280; }
  long long i0 = (long long)base*1024 + threadIdx.x;
#pragma unroll
  for (int k2 = 0; k2 < 4; ++k2) {
    long long i = i0 + k2*256;   // float4 index, coalesced
    float4 v = ((const float4*)src)[i];
    half4v h; h[0]=(f16)v.x; h[1]=(f16)v.y; h[2]=(f16)v.z; h[3]=(f16)v.w;
    *(half4v*)(dst + i*4) = h;
  }
}

// ---------------- TM x TN f16 MFMA GEMM (BK-deep K-tiles), C = A * Bw^T + bias ----
// MODE 0: QKV -> q8/k8 (u8 quant, [b,h,s,d]) and vT (f16, [b,h,d,s])
// MODE 1: proj -> f32 out [t, f]
// Proven configs: gemm0 128x128 BK128 MW2, gemm1 64x64 BK128 MW4 (R14/R17
// tiling/residency variations all neutral).
template<int TM, int TN, int BK, int MW, int MODE>
__global__ __launch_bounds__(256, MW) void gemm_kernel(
    const f16* __restrict__ A, const f16* __restrict__ Bw, const float* __restrict__ bias,
    unsigned char* __restrict__ q8, unsigned char* __restrict__ k8, f16* __restrict__ vT,
    float* __restrict__ outp, int K)
{
  constexpr int MT = TM / 32;   // m-subtiles per wave
  constexpr int NT = TN / 32;   // n-subtiles per wave
  constexpr int G  = BK / 8;    // 16B groups per LDS row
  __shared__ f16 As[TM*BK];
  __shared__ f16 Bs[TN*BK];
  const int tid = threadIdx.x;
  const int wave = tid >> 6, lane = tid & 63;
  const int lq = lane >> 4, li = lane & 15;
  const int m0 = blockIdx.y * TM, n0 = blockIdx.x * TN;
  const int wm = (wave & 1) * (TM/2), wn = (wave >> 1) * (TN/2);
  floatx4 acc[MT][NT] = {};

  const int kIters = K / BK;
  for (int kt = 0; kt < kIters; ++kt) {
    __syncthreads();
#pragma unroll
    for (int r = 0; r < TM*BK/2048; ++r) {
      int slot = r*256 + tid;
      int row = slot / G, c = slot % G, g = c ^ (row & (G-1));
      gld16(A + (size_t)(m0+row)*K + kt*BK + g*8, As + slot*8);
    }
#pragma unroll
    for (int r = 0; r < TN*BK/2048; ++r) {
      int slot = r*256 + tid;
      int row = slot / G, c = slot % G, g = c ^ (row & (G-1));
      gld16(Bw + (size_t)(n0+row)*K + kt*BK + g*8, Bs + slot*8);
    }
    __syncthreads();
#pragma unroll
    for (int ks = 0; ks < BK/32; ++ks) {
      half8 af[MT], bf[NT];
      int kc = ks*4 + lq;
#pragma unroll
      for (int t = 0; t < MT; ++t) {
        int am = wm + t*16 + li;
        af[t] = *(const half8*)&As[am*BK + (kc ^ (am & (G-1)))*8];
      }
#pragma unroll
      for (int t = 0; t < NT; ++t) {
        int bn = wn + t*16 + li;
        bf[t] = *(const half8*)&Bs[bn*BK + (kc ^ (bn & (G-1)))*8];
      }
#pragma unroll
      for (int mt = 0; mt < MT; ++mt)
#pragma unroll
        for (int nt = 0; nt < NT; ++nt)
          acc[mt][nt] = __builtin_amdgcn_mfma_f32_16x16x32_f16(af[mt], bf[nt], acc[mt][nt], 0, 0, 0);
    }
  }

#pragma unroll
  for (int mt = 0; mt < MT; ++mt) {
#pragma unroll
    for (int nt = 0; nt < NT; ++nt) {
      int f = n0 + wn + nt*16 + li;                 // output feature (col, from B)
      float bb = bias[f];
      if (MODE == 0) {
        int which = f >> 10, cc = f & 1023, h = cc >> 6, d = cc & 63;
        int t0 = m0 + wm + mt*16 + lq*4;            // token (row, from A), 4 consecutive
        int b = t0 >> 10, s0 = t0 & 1023;
        if (which == 2) {
          half4v hv;
#pragma unroll
          for (int r = 0; r < 4; ++r) hv[r] = (f16)(acc[mt][nt][r] + bb);
          *(half4v*)&vT[((size_t)((b*HEADS + h)*HD + d))*SEQ + s0] = hv;
        } else {
          unsigned char* dst = (which == 0) ? q8 : k8;
#pragma unroll
          for (int r = 0; r < 4; ++r) {
            float v = acc[mt][nt][r] + bb;
            int u = (int)floorf(v * 16.0f + 128.5f);
            u = u < 0 ? 0 : (u > 255 ? 255 : u);
            dst[((size_t)((b*HEADS + h)*SEQ + s0 + r))*HD + d] = (unsigned char)u;
          }
        }
      } else {
#pragma unroll
        for (int r = 0; r < 4; ++r) {
          int t = m0 + wm + mt*16 + lq*4 + r;
          outp[(size_t)t*DIMC + f] = acc[mt][nt][r] + bb;
        }
      }
    }
  }
}

// ---------------- Laplacian attention + depthwise conv, y16 out ----------------
// R19 (on top of R18's 32-row/1024-block split):
// (1) k8s chunk XOR-swizzle: R18's kk reads were 4-way bank conflicts (4
//     jt-groups read rows 512B apart = same bank quad). Store row r chunk c at
//     slot c^((r>>3)&3) via pre-swizzled GLOBAL source (linear LDS dest, rule
//     #21); read with key c4^jt -> 4 groups hit 4 disjoint bank quads.
// (2) vTs LDS staging DELETED: R18 had zero cross-wave vTs reuse (each wave
//     reads only d-strip wave*16..+15). Each wave now loads its 4 B-frags
//     (16 VGPR) directly from vTg at loop top (issue-early/use-late; vT rows
//     are XCD-local L2: same-bh blocks share lin&7).
// (3) Double-buffered k8s + sfrag -> ONE barrier per jb (stage k[jb+1] at top,
//     SAD reads k[jb] staged last iter -> staging latency hidden under SAD).
// LDS 36992B (4 blocks/CU). Barriers/block 19 -> 11.
__global__ __launch_bounds__(256, 4) void attn_kernel(
    const unsigned char* __restrict__ q8g, const unsigned char* __restrict__ k8g,
    const f16* __restrict__ vTg, const float* __restrict__ dwcw, const float* __restrict__ dwcb,
    f16* __restrict__ y16)
{
  __shared__ unsigned char q8s[32*64];     //  2KB
  __shared__ unsigned char k8s[2][128*64]; // 16KB double-buffered
  __shared__ f16 sfrag[2][8*64*8];         // 16KB double-buffered A-frag scores
  __shared__ float rspart[32*16];          //  2KB
  __shared__ float rowsum[32];             // total 36992B -> 4 blocks/CU

  const int tid = threadIdx.x;
  const int lin = blockIdx.x + 16 * blockIdx.y;      // 0..1023
  const int bh = (lin & 7) * 4 + ((lin >> 3) & 3);   // XCD-grouped head index
  const int i0 = (lin >> 5) * 32;                    // 32 i-blocks of 32 rows
  const int lane = tid & 63, wave = tid >> 6;
  const int lq = lane >> 4, li = lane & 15;
  const int iL = tid & 15, jt = tid >> 4;       // phase-1 mapping
  const int ksj = jt >> 2, qj = jt & 3;
  const int scs = jt & 3;                       // chunk-swizzle read key

  { // stage q tile (32x64B, waves 0-1) + k8s[0] with chunk swizzle
    if (tid < 128)
      gld16(q8g + ((size_t)(bh*SEQ) + i0)*HD + tid*16, q8s + tid*16);
#pragma unroll
    for (int r = 0; r < 2; ++r) {
      int slot = r*256 + tid;
      int row = slot >> 2, c4 = slot & 3, sc4 = c4 ^ ((row >> 3) & 3);
      gld16(k8g + ((size_t)(bh*SEQ) + row)*HD + sc4*16, k8s[0] + slot*16);
    }
  }
  __syncthreads();

  // q rows {iL, iL+16} into regs (32 u32)
  unsigned qr[2][16];
#pragma unroll
  for (int n = 0; n < 2; ++n)
#pragma unroll
    for (int c4 = 0; c4 < 4; ++c4) {
      uint4 t = *(const uint4*)&q8s[(iL + n*16)*64 + c4*16];
      qr[n][c4*4+0] = t.x; qr[n][c4*4+1] = t.y; qr[n][c4*4+2] = t.z; qr[n][c4*4+3] = t.w;
    }

  float rs[2] = {0.f, 0.f};
  floatx4 pacc[2] = {};                  // this wave owns d-strip wave*16..+15
  const f16* vbase = vTg + ((size_t)(bh*HD) + wave*16 + li)*SEQ;

  for (int jb = 0; jb < 8; ++jb) {
    const int j0 = jb * 128;
    const int cur = jb & 1;

    // stage NEXT k tile (consumed in iter jb+1; lands by this iter's barrier)
    if (jb < 7) {
#pragma unroll
      for (int r = 0; r < 2; ++r) {
        int slot = r*256 + tid;
        int row = slot >> 2, c4 = slot & 3, sc4 = c4 ^ ((row >> 3) & 3);
        gld16(k8g + ((size_t)(bh*SEQ) + j0 + 128 + row)*HD + sc4*16,
              k8s[cur ^ 1] + slot*16);
      }
    }
    // issue this iter's V B-frags (global->reg, waited at MFMA use)
    half8 vfrag[4];
#pragma unroll
    for (int ks = 0; ks < 4; ++ks)
      vfrag[ks] = *(const half8*)(vbase + j0 + (ks*4 + lq)*8);

    // ---- phase 1: SAD distances from k8s[cur] (staged last iter) ----
    unsigned sacc[2][8] = {};
#pragma unroll
    for (int c4 = 0; c4 < 4; ++c4) {
      uint4 kk[8];
#pragma unroll
      for (int jj = 0; jj < 8; ++jj)
        kk[jj] = *(const uint4*)&k8s[cur][(jt*8 + jj)*64 + ((c4 ^ scs) << 4)];
#pragma unroll
      for (int n = 0; n < 2; ++n)
#pragma unroll
        for (int jj = 0; jj < 8; ++jj) {
          sacc[n][jj] = sadU8(qr[n][c4*4+0], kk[jj].x, sacc[n][jj]);
          sacc[n][jj] = sadU8(qr[n][c4*4+1], kk[jj].y, sacc[n][jj]);
          sacc[n][jj] = sadU8(qr[n][c4*4+2], kk[jj].z, sacc[n][jj]);
          sacc[n][jj] = sadU8(qr[n][c4*4+3], kk[jj].w, sacc[n][jj]);
        }
    }
    // kern = exp(-dist/16), dist = sad/16  ->  exp2(-sad * log2(e)/256)
#pragma unroll
    for (int n = 0; n < 2; ++n) {
      half8 sv;
#pragma unroll
      for (int jj = 0; jj < 8; ++jj) {
        float sf = exp2f(-0.0056355275f * (float)sacc[n][jj]);
        rs[n] += sf;
        sv[jj] = (f16)sf;
      }
      *(half8*)&sfrag[cur][((n*4 + ksj)*64 + qj*16 + iL)*8] = sv;
    }
    __syncthreads();   // sfrag[cur] ready; k8s[cur^1] landed (vmcnt drain)

    // ---- phase 2: PV via MFMA, wave tile 32i x 16d, B from regs ----
#pragma unroll
    for (int ks = 0; ks < 4; ++ks) {
      half8 a0 = *(const half8*)&sfrag[cur][((0*4 + ks)*64 + lane)*8];
      half8 a1 = *(const half8*)&sfrag[cur][((1*4 + ks)*64 + lane)*8];
      pacc[0] = __builtin_amdgcn_mfma_f32_16x16x32_f16(a0, vfrag[ks], pacc[0], 0, 0, 0);
      pacc[1] = __builtin_amdgcn_mfma_f32_16x16x32_f16(a1, vfrag[ks], pacc[1], 0, 0, 0);
    }
  }

  // rowsum reduction across the 16 j-slices
#pragma unroll
  for (int n = 0; n < 2; ++n) rspart[(iL + n*16)*16 + jt] = rs[n];
  __syncthreads();
  if (tid < 32) {
    float s = 0.f;
#pragma unroll
    for (int t = 0; t < 16; ++t) s += rspart[tid*16 + t];
    rowsum[tid] = s + 1e-6f;
  }
  __syncthreads();

  // epilogue: normalize + depthwise conv + store y16 [b,s,h*64+d]
  const int b = bh >> 4, h = bh & 15;
  {
    int d = wave*16 + li;
    int c = h*64 + d;
    float w0 = dwcw[c*3+0], w1 = dwcw[c*3+1], w2 = dwcw[c*3+2], cb = dwcb[c];
    const f16* vrow = vTg + ((size_t)(bh*HD) + d)*SEQ;
#pragma unroll
    for (int mt = 0; mt < 2; ++mt) {
      int s0 = i0 + mt*16 + lq*4;                  // first of 4 consecutive rows
      float vv[6];
#pragma unroll
      for (int e = 0; e < 6; ++e) {
        int s = s0 - 1 + e;
        vv[e] = (s >= 0 && s < SEQ) ? (float)vrow[s] : 0.f;
      }
#pragma unroll
      for (int r = 0; r < 4; ++r) {
        int ii = mt*16 + lq*4 + r;
        float val = pacc[mt][r] / rowsum[ii];
        val += w0*vv[r] + w1*vv[r+1] + w2*vv[r+2] + cb;
        int s = i0 + ii;
        y16[((size_t)(b*SEQ + s))*DIMC + c] = (f16)val;
      }
    }
  }
}

extern "C" void kernel_launch(void* const* d_in, const int* in_sizes, int n_in,
                              void* d_out, int out_size, void* d_ws, size_t ws_size,
                              hipStream_t stream) {
  const float* x      = (const float*)d_in[0];
  const float* qkv_w  = (const float*)d_in[1];
  const float* qkv_b  = (const float*)d_in[2];
  const float* proj_w = (const float*)d_in[3];
  const float* proj_b = (const float*)d_in[4];
  const float* dwc_w  = (const float*)d_in[5];
  const float* dwc_b  = (const float*)d_in[6];
  float* out = (float*)d_out;

  char* ws = (char*)d_ws;
  f16* x16  = (f16*)(ws);                         //  4 MB
  f16* wq16 = (f16*)(ws + (4ll<<20));             //  6 MB
  f16* wp16 = (f16*)(ws + (10ll<<20));            //  2 MB
  unsigned char* q8 = (unsigned char*)(ws + (12ll<<20));  // 2 MB
  unsigned char* k8 = (unsigned char*)(ws + (14ll<<20));  // 2 MB
  f16* vT   = (f16*)(ws + (16ll<<20));            //  4 MB
  f16* y16  = (f16*)(ws + (20ll<<20));            //  4 MB (total 24 MB)

  cvt_kernel<<<1536, 256, 0, stream>>>(x, qkv_w, proj_w, x16, wq16, wp16);
  // gemm0: 128x128 tile, BK=128 (8 K-iters) — grid 24x16 = 384 blocks (proven)
  gemm_kernel<128,128,128,2,0><<<dim3(24, 16), 256, 0, stream>>>(x16, wq16, qkv_b, q8, k8, vT, nullptr, DIMC);
  // attn: 1024 blocks (32 bh x 32 i-blocks of 32 rows) = 4 blocks/CU
  attn_kernel<<<dim3(16, 64), 256, 0, stream>>>(q8, k8, vT, dwc_w, dwc_b, y16);
  // gemm1: 64x64 tile, BK=128 — grid 16x32 = 512 blocks (proven)
  gemm_kernel<64,64,128,4,1><<<dim3(16, 32), 256, 0, stream>>>(y16, wp16, proj_b, nullptr, nullptr, nullptr, out, DIMC);
}